// Round 5
// baseline (191.071 us; speedup 1.0000x reference)
//
#include <hip/hip_runtime.h>
#include <hip/hip_cooperative_groups.h>
#include <math.h>

namespace cg = cooperative_groups;

#define NS 256000
#define N1 512            // FFT over n1: radix 8,8,8
#define N2 500            // FFT over n2: radices 5,5,5,4
#define PI_F 3.14159265358979323846f

typedef float2 cplx;

__device__ __forceinline__ cplx cadd(cplx a, cplx b){ return make_float2(a.x+b.x, a.y+b.y); }
__device__ __forceinline__ cplx csub(cplx a, cplx b){ return make_float2(a.x-b.x, a.y-b.y); }
__device__ __forceinline__ cplx cmul(cplx a, cplx b){ return make_float2(a.x*b.x-a.y*b.y, a.x*b.y+a.y*b.x); }
__device__ __forceinline__ cplx cmulc(cplx a, cplx b){ return make_float2(a.x*b.x+a.y*b.y, a.y*b.x-a.x*b.y); }
__device__ __forceinline__ cplx crotf(cplx v, float ang){
    float sn = __sinf(ang), cs = __cosf(ang);
    return make_float2(v.x*cs - v.y*sn, v.x*sn + v.y*cs);
}
__device__ __forceinline__ int PX(int e){ return e + (e>>4); }
__device__ __forceinline__ int rev8_3(int k){ return ((k&7)<<6) | (k&0x38) | (k>>6); }

template<bool INV>
__device__ __forceinline__ void dft4(const cplx* a, cplx* b){
    cplx t0=cadd(a[0],a[2]), t1=csub(a[0],a[2]), t2=cadd(a[1],a[3]), t3=csub(a[1],a[3]);
    b[0]=cadd(t0,t2); b[2]=csub(t0,t2);
    if(!INV){ b[1]=make_float2(t1.x+t3.y, t1.y-t3.x); b[3]=make_float2(t1.x-t3.y, t1.y+t3.x); }
    else    { b[1]=make_float2(t1.x-t3.y, t1.y+t3.x); b[3]=make_float2(t1.x+t3.y, t1.y-t3.x); }
}

template<bool INV>
__device__ __forceinline__ void dft8(const cplx* a, cplx* b){
    cplx ev[4]={a[0],a[2],a[4],a[6]}, od[4]={a[1],a[3],a[5],a[7]};
    cplx C[4], D[4];
    dft4<INV>(ev, C); dft4<INV>(od, D);
    const float s = 0.70710678118654752f;
    const float sg = INV ? 1.f : -1.f;
    cplx d1 = cmul(D[1], make_float2( s, sg*s));
    cplx d2 = cmul(D[2], make_float2(0.f, sg ));
    cplx d3 = cmul(D[3], make_float2(-s, sg*s));
    b[0]=cadd(C[0],D[0]); b[4]=csub(C[0],D[0]);
    b[1]=cadd(C[1],d1);   b[5]=csub(C[1],d1);
    b[2]=cadd(C[2],d2);   b[6]=csub(C[2],d2);
    b[3]=cadd(C[3],d3);   b[7]=csub(C[3],d3);
}

template<bool INV>
__device__ __forceinline__ void dft5(const cplx* a, cplx* b){
    const float c1=0.30901699437494742f, s1=0.95105651629515357f;
    const float c2=-0.80901699437494745f, s2=0.58778525229247312f;
    const float sg = INV ? 1.f : -1.f;
    cplx W[5];
    W[0]=make_float2(1.f,0.f);
    W[1]=make_float2(c1, sg*s1); W[2]=make_float2(c2, sg*s2);
    W[3]=make_float2(c2,-sg*s2); W[4]=make_float2(c1,-sg*s1);
#pragma unroll
    for(int u=0;u<5;++u){
        cplx acc = a[0];
        int idx = 0;
#pragma unroll
        for(int r=1;r<5;++r){
            idx += u; if(idx >= 5) idx -= 5;
            acc = cadd(acc, cmul(a[r], W[idx]));
        }
        b[u] = acc;
    }
}

// In-place stage on a wave-private LDS column (compile-time shape).
template<int R, int L, int TMUL, bool INV, int NN>
__device__ __forceinline__ void wstage(cplx* Uw, const cplx* tab, int lane){
    constexpr int m = L / R;
    constexpr int nb = NN / R;
#pragma unroll
    for(int it = 0; it < (nb + 63) / 64; ++it){
        int beta = lane + it*64;
        if(beta < nb){
            int blk = beta / m;
            int j = beta - blk*m;
            int base = blk*L + j;
            cplx a[R];
#pragma unroll
            for(int t=0;t<R;++t) a[t] = Uw[PX(base + m*t)];
            if(INV){
#pragma unroll
                for(int t=1;t<R;++t) a[t] = cmulc(a[t], tab[TMUL*j*t]);
            }
            cplx bb[R];
            if constexpr (R==4) dft4<INV>(a,bb);
            else if constexpr (R==5) dft5<INV>(a,bb);
            else dft8<INV>(a,bb);
            if(!INV){
#pragma unroll
                for(int t=1;t<R;++t) bb[t] = cmul(bb[t], tab[TMUL*j*t]);
            }
#pragma unroll
            for(int t=0;t<R;++t) Uw[PX(base + m*t)] = bb[t];
        }
    }
}

template<int NTAB>
__device__ __forceinline__ void build_tab(cplx* tab, int tid){
    const float step = -2.f*PI_F/(float)NTAB;
    for(int i = tid; i < NTAB; i += 256){
        float a = step*(float)i;
        tab[i] = make_float2(__cosf(a), __sinf(a));
    }
}

// ======================= phase device functions ============================
// tid is the 0..255 within-half index. Each contains a fixed barrier sequence;
// callers guarantee all threads of a block execute the same sequence.

__device__ void dev_kT1(const float* __restrict__ fm, float* __restrict__ mm,
                        int b, int tid, float* scratch){
    float* Aarr = scratch;          // 500
    float* wfr  = scratch + 500;    // 500
    float* part = scratch + 1000;   // 256
    for(int f = tid; f < 500; f += 256){
        long long i0 = ((long long)f*255999LL + 498LL)/499LL;
        long long i1 = ((long long)(f+1)*255999LL + 498LL)/499LL;
        long long cnt = i1 - i0;
        long long sumi = (i0 + i1 - 1)*cnt/2;
        long long num = 499LL*sumi - cnt*(long long)f*255999LL;
        Aarr[f] = (float)((double)num / 255999.0);
    }
    __syncthreads();
    for(int f = tid; f < 500; f += 256){
        long long i0 = ((long long)f*255999LL + 498LL)/499LL;
        long long i1 = ((long long)(f+1)*255999LL + 498LL)/499LL;
        double wv;
        if(f < 499) wv = (double)(i1 - i0) - (double)Aarr[f] + (f > 0 ? (double)Aarr[f-1] : 0.0);
        else        wv = (double)Aarr[498] + 1.0;
        wfr[f] = (float)(wv / (double)NS);
    }
    __syncthreads();
    const int k = tid & 63, seg = tid >> 6;
    float acc = 0.f;
    for(int f = seg*125; f < seg*125 + 125; ++f)
        acc += wfr[f] * fm[(b*500 + f)*64 + k];
    part[seg*64 + k] = acc;
    __syncthreads();
    if(tid < 64) mm[b*64 + tid] = part[tid] + part[64+tid] + part[128+tid] + part[192+tid];
}

__device__ void dev_kA(const float* __restrict__ noise, cplx* __restrict__ Y,
                       int item, int tid, cplx* sTab, cplx (*sU)[545]){
    const int lane = tid & 63, w = tid >> 6;
    const int b = item / 125;
    const int n2base = (item - b*125) * 4;
    build_tab<512>(sTab, tid);
    __syncthreads();
    const float* xb = noise + b*NS + n2base;
    for(int i = tid; i < 512*4; i += 256){
        int n1 = i >> 2, ws = i & 3;
        sU[ws][PX(n1)] = make_float2(xb[n1*500 + ws], 0.f);
    }
    __syncthreads();
    cplx* Uw = sU[w];
    wstage<8,512, 1,false,512>(Uw, sTab, lane); __syncthreads();
    wstage<8, 64, 8,false,512>(Uw, sTab, lane); __syncthreads();
    wstage<8,  8,64,false,512>(Uw, sTab, lane); __syncthreads();
    const int n2 = n2base + w;
    cplx* yp = Y + (b*N2 + n2)*N1;
    const float tw = -2.f*PI_F/(float)NS;
#pragma unroll
    for(int t = 0; t < 8; ++t){
        int p = lane + 64*t;
        int k1 = rev8_3(p);
        cplx v = Uw[PX(p)];
        v = crotf(v, tw*(float)(n2*k1));
        yp[p] = v;
    }
}

__device__ void dev_kB(cplx* __restrict__ Y, const float* __restrict__ mm,
                       int item, int tid, cplx* sTab, cplx (*sU)[545],
                       float* sLog, float* sMM){
    const int lane = tid & 63, w = tid >> 6;
    const int b = item >> 7;
    const int p1base = (item & 127) * 4;
    build_tab<500>(sTab, tid);
    if(tid < 64){
        double a = 1.3010299956639812;            // log10(20)
        double bb = 4.0423785980704266;           // log10(11025)
        double e = a + (bb - a)*(double)tid/63.0;
        sLog[tid] = (float)(2.302585092994046 * e);  // ln(filter_freq); +1e-7 negligible
        sMM[tid] = mm[b*64 + tid];
    }
    __syncthreads();
    cplx* yb = Y + b*NS + p1base;
    for(int i = tid; i < 500*4; i += 256){
        int n2 = i >> 2, ws = i & 3;
        sU[ws][PX(n2)] = yb[n2*N1 + ws];
    }
    __syncthreads();
    cplx* Uw = sU[w];
    wstage<5,500,  1,false,500>(Uw, sTab, lane); __syncthreads();
    wstage<5,100,  5,false,500>(Uw, sTab, lane); __syncthreads();
    wstage<5, 20, 25,false,500>(Uw, sTab, lane); __syncthreads();
    wstage<4,  4,125,false,500>(Uw, sTab, lane); __syncthreads();
    {
        const int k1 = rev8_3(p1base + w);
        const float invN = 1.f/(float)NS;
#pragma unroll
        for(int t = 0; t < 8; ++t){
            int p = lane + 64*t;
            if(p < 500){
                int t1 = p/100; int r = p - 100*t1;
                int t2 = r/20;  r -= 20*t2;
                int t3 = r>>2;  int t4 = r & 3;
                int k2 = t1 + 5*t2 + 25*t3 + 125*t4;
                int kf = k1 + N1*k2;
                int kk = min(kf, NS - kf);
                float lf = logf((float)kk*(22050.f/(float)NS) + 1e-7f);
                float wsum = 0.f, wmv = 0.f;
#pragma unroll
                for(int j = 0; j < 64; ++j){
                    float d = lf - sLog[j];
                    float e = __expf(-2.f*d*d);
                    wsum += e;
                    wmv += e*sMM[j];
                }
                float h = wmv/(wsum + 1e-7f)*invN;
                cplx v = Uw[PX(p)];
                Uw[PX(p)] = make_float2(v.x*h, v.y*h);
            }
        }
    }
    __syncthreads();
    wstage<4,  4,125,true,500>(Uw, sTab, lane); __syncthreads();
    wstage<5, 20, 25,true,500>(Uw, sTab, lane); __syncthreads();
    wstage<5,100,  5,true,500>(Uw, sTab, lane); __syncthreads();
    wstage<5,500,  1,true,500>(Uw, sTab, lane); __syncthreads();
    const float tw = 2.f*PI_F/(float)NS;
    for(int i = tid; i < 500*4; i += 256){
        int n2 = i >> 2, ws = i & 3;
        int k1 = rev8_3(p1base + ws);
        cplx v = sU[ws][PX(n2)];
        v = crotf(v, tw*(float)(n2*k1));
        yb[n2*N1 + ws] = v;
    }
}

__device__ void dev_kC(const cplx* __restrict__ Y, float* __restrict__ out,
                       int item, int tid, cplx* sTab, cplx (*sU)[545]){
    const int lane = tid & 63, w = tid >> 6;
    const int b = item / 125;
    const int n2base = (item - b*125) * 4;
    build_tab<512>(sTab, tid);
    __syncthreads();
    {
        const cplx* yp = Y + (b*N2 + n2base + w)*N1;
        cplx* Uw = sU[w];
#pragma unroll
        for(int t = 0; t < 8; ++t){
            int p = lane + 64*t;
            Uw[PX(p)] = yp[p];
        }
    }
    __syncthreads();
    cplx* Uw = sU[w];
    wstage<8,  8,64,true,512>(Uw, sTab, lane); __syncthreads();
    wstage<8, 64, 8,true,512>(Uw, sTab, lane); __syncthreads();
    wstage<8,512, 1,true,512>(Uw, sTab, lane); __syncthreads();
    float* ob = out + b*NS + n2base;
    for(int i = tid; i < 512*4; i += 256){
        int n1 = i >> 2, ws = i & 3;
        ob[n1*500 + ws] = sU[ws][PX(n1)].x;
    }
}

// ======================= fused cooperative kernel ==========================
// grid = 256 blocks (1/CU guaranteed) x 512 threads; half h handles item 2*bid+h.
// Work pairing keeps both halves of a block on the same path (same barrier seq).
__global__ __launch_bounds__(512, 1) void kFused(const float* __restrict__ fm,
                                                 const float* __restrict__ noise,
                                                 float* __restrict__ out,
                                                 cplx* __restrict__ Y,
                                                 float* __restrict__ mm){
    __shared__ cplx sTab[512];
    __shared__ cplx sU[8][545];
    __shared__ float sLog[64];
    __shared__ float sMM[64];
    cg::grid_group grid = cg::this_grid();
    const int tid = threadIdx.x;
    const int half = tid >> 8, tid8 = tid & 255;
    cplx (*sUh)[545] = &sU[half*4];
    const int item = blockIdx.x*2 + half;

    // Phase 1: items 0..499 -> kA; 500..503 -> kT1; rest idle
    if(item < 500)       dev_kA(noise, Y, item, tid8, sTab, sUh);
    else if(item < 504)  dev_kT1(fm, mm, item - 500, tid8, (float*)&sUh[0][0]);
    grid.sync();

    // Phase 2: items 0..511 -> kB (uniform)
    dev_kB(Y, mm, item, tid8, sTab, sUh, sLog, sMM);
    grid.sync();

    // Phase 3: items 0..499 -> kC
    if(item < 500) dev_kC(Y, out, item, tid8, sTab, sUh);
}

// ======================= fallback standalone kernels =======================
__global__ __launch_bounds__(256) void kT1s(const float* __restrict__ fm,
                                            float* __restrict__ mm){
    __shared__ float scratch[1280];
    dev_kT1(fm, mm, blockIdx.x, threadIdx.x, scratch);
}
__global__ __launch_bounds__(256) void kAs(const float* __restrict__ noise,
                                           cplx* __restrict__ Y){
    __shared__ cplx sTab[512];
    __shared__ cplx sU[4][545];
    dev_kA(noise, Y, blockIdx.x, threadIdx.x, sTab, sU);
}
__global__ __launch_bounds__(256) void kBs(cplx* __restrict__ Y,
                                           const float* __restrict__ mm){
    __shared__ cplx sTab[512];
    __shared__ cplx sU[4][545];
    __shared__ float sLog[64];
    __shared__ float sMM[64];
    dev_kB(Y, mm, blockIdx.x, threadIdx.x, sTab, sU, sLog, sMM);
}
__global__ __launch_bounds__(256) void kCs(const cplx* __restrict__ Y,
                                           float* __restrict__ out){
    __shared__ cplx sTab[512];
    __shared__ cplx sU[4][545];
    dev_kC(Y, out, blockIdx.x, threadIdx.x, sTab, sU);
}

// ---------------------------------------------------------------------------
extern "C" void kernel_launch(void* const* d_in, const int* in_sizes, int n_in,
                              void* d_out, int out_size, void* d_ws, size_t ws_size,
                              hipStream_t stream) {
    const float* fm = (const float*)d_in[0];     // (4,500,64)
    const float* noise = (const float*)d_in[1];  // (4,256000)
    float* out = (float*)d_out;

    char* ws = (char*)d_ws;
    cplx*  Y  = (cplx*)ws;                       //  8,192,000 B
    float* mm = (float*)(ws + 8192000);          //      1,024 B

    void* args[] = { (void*)&fm, (void*)&noise, (void*)&out, (void*)&Y, (void*)&mm };
    hipError_t err = hipLaunchCooperativeKernel((const void*)kFused, dim3(256),
                                                dim3(512), args, 0, stream);
    if(err != hipSuccess){
        (void)hipGetLastError();   // clear sticky error; fall back to 4 launches
        kT1s<<<4,   256, 0, stream>>>(fm, mm);
        kAs <<<500, 256, 0, stream>>>(noise, Y);
        kBs <<<512, 256, 0, stream>>>(Y, mm);
        kCs <<<500, 256, 0, stream>>>(Y, out);
    }
}

// Round 7
// 116.929 us; speedup vs baseline: 1.6341x; 1.6341x over previous
//
#include <hip/hip_runtime.h>
#include <math.h>

#define NS 256000
#define N1 512            // FFT over n1: radix 8,8,8
#define N2 500            // FFT over n2: radices 5,5,5,4
#define PI_F 3.14159265358979323846f

typedef float2 cplx;

__device__ __forceinline__ cplx cadd(cplx a, cplx b){ return make_float2(a.x+b.x, a.y+b.y); }
__device__ __forceinline__ cplx csub(cplx a, cplx b){ return make_float2(a.x-b.x, a.y-b.y); }
__device__ __forceinline__ cplx cmul(cplx a, cplx b){ return make_float2(a.x*b.x-a.y*b.y, a.x*b.y+a.y*b.x); }
__device__ __forceinline__ cplx cmulc(cplx a, cplx b){ return make_float2(a.x*b.x+a.y*b.y, a.y*b.x-a.x*b.y); }
__device__ __forceinline__ cplx crotf(cplx v, float ang){
    float sn = __sinf(ang), cs = __cosf(ang);
    return make_float2(v.x*cs - v.y*sn, v.x*sn + v.y*cs);
}
__device__ __forceinline__ int PX(int e){ return e + (e>>4); }
__device__ __forceinline__ int rev8_3(int k){ return ((k&7)<<6) | (k&0x38) | (k>>6); }

// Intra-wave LDS fence: DS pipe is in-order per wave, so visibility only needs
// (a) the wave's outstanding DS writes drained (lgkmcnt(0)) and (b) a compiler
// scheduling fence so stage-k reads aren't hoisted above stage-(k-1) writes.
// 0xC07F = vmcnt(63) expcnt(7) lgkmcnt(0)  -> waits only on LDS.
__device__ __forceinline__ void wave_fence(){
    __builtin_amdgcn_s_waitcnt(0xC07F);
    __builtin_amdgcn_wave_barrier();
}

template<bool INV>
__device__ __forceinline__ void dft4(const cplx* a, cplx* b){
    cplx t0=cadd(a[0],a[2]), t1=csub(a[0],a[2]), t2=cadd(a[1],a[3]), t3=csub(a[1],a[3]);
    b[0]=cadd(t0,t2); b[2]=csub(t0,t2);
    if(!INV){ b[1]=make_float2(t1.x+t3.y, t1.y-t3.x); b[3]=make_float2(t1.x-t3.y, t1.y+t3.x); }
    else    { b[1]=make_float2(t1.x-t3.y, t1.y+t3.x); b[3]=make_float2(t1.x+t3.y, t1.y-t3.x); }
}

template<bool INV>
__device__ __forceinline__ void dft8(const cplx* a, cplx* b){
    cplx ev[4]={a[0],a[2],a[4],a[6]}, od[4]={a[1],a[3],a[5],a[7]};
    cplx C[4], D[4];
    dft4<INV>(ev, C); dft4<INV>(od, D);
    const float s = 0.70710678118654752f;
    const float sg = INV ? 1.f : -1.f;
    cplx d1 = cmul(D[1], make_float2( s, sg*s));
    cplx d2 = cmul(D[2], make_float2(0.f, sg ));
    cplx d3 = cmul(D[3], make_float2(-s, sg*s));
    b[0]=cadd(C[0],D[0]); b[4]=csub(C[0],D[0]);
    b[1]=cadd(C[1],d1);   b[5]=csub(C[1],d1);
    b[2]=cadd(C[2],d2);   b[6]=csub(C[2],d2);
    b[3]=cadd(C[3],d3);   b[7]=csub(C[3],d3);
}

template<bool INV>
__device__ __forceinline__ void dft5(const cplx* a, cplx* b){
    const float c1=0.30901699437494742f, s1=0.95105651629515357f;
    const float c2=-0.80901699437494745f, s2=0.58778525229247312f;
    const float sg = INV ? 1.f : -1.f;
    cplx W[5];
    W[0]=make_float2(1.f,0.f);
    W[1]=make_float2(c1, sg*s1); W[2]=make_float2(c2, sg*s2);
    W[3]=make_float2(c2,-sg*s2); W[4]=make_float2(c1,-sg*s1);
#pragma unroll
    for(int u=0;u<5;++u){
        cplx acc = a[0];
        int idx = 0;
#pragma unroll
        for(int r=1;r<5;++r){
            idx += u; if(idx >= 5) idx -= 5;
            acc = cadd(acc, cmul(a[r], W[idx]));
        }
        b[u] = acc;
    }
}

// In-place stage on a wave-private LDS column (compile-time shape).
// Caller must wave_fence() between dependent stages.
template<int R, int L, int TMUL, bool INV, int NN>
__device__ __forceinline__ void wstage(cplx* Uw, const cplx* tab, int lane){
    constexpr int m = L / R;
    constexpr int nb = NN / R;
#pragma unroll
    for(int it = 0; it < (nb + 63) / 64; ++it){
        int beta = lane + it*64;
        if(beta < nb){
            int blk = beta / m;
            int j = beta - blk*m;
            int base = blk*L + j;
            cplx a[R];
#pragma unroll
            for(int t=0;t<R;++t) a[t] = Uw[PX(base + m*t)];
            if(INV){
#pragma unroll
                for(int t=1;t<R;++t) a[t] = cmulc(a[t], tab[TMUL*j*t]);
            }
            cplx bb[R];
            if constexpr (R==4) dft4<INV>(a,bb);
            else if constexpr (R==5) dft5<INV>(a,bb);
            else dft8<INV>(a,bb);
            if(!INV){
#pragma unroll
                for(int t=1;t<R;++t) bb[t] = cmul(bb[t], tab[TMUL*j*t]);
            }
#pragma unroll
            for(int t=0;t<R;++t) Uw[PX(base + m*t)] = bb[t];
        }
    }
}

template<int NTAB>
__device__ __forceinline__ void build_tab(cplx* tab, int tid){
    const float step = -2.f*PI_F/(float)NTAB;
    for(int i = tid; i < NTAB; i += 256){
        float a = step*(float)i;
        tab[i] = make_float2(__cosf(a), __sinf(a));
    }
}

__device__ void dev_kT1(const float* __restrict__ fm, float* __restrict__ mm,
                        int b, int tid, float* scratch){
    float* Aarr = scratch;          // 500
    float* wfr  = scratch + 500;    // 500
    float* part = scratch + 1000;   // 256
    for(int f = tid; f < 500; f += 256){
        long long i0 = ((long long)f*255999LL + 498LL)/499LL;
        long long i1 = ((long long)(f+1)*255999LL + 498LL)/499LL;
        long long cnt = i1 - i0;
        long long sumi = (i0 + i1 - 1)*cnt/2;
        long long num = 499LL*sumi - cnt*(long long)f*255999LL;
        Aarr[f] = (float)((double)num / 255999.0);
    }
    __syncthreads();
    for(int f = tid; f < 500; f += 256){
        long long i0 = ((long long)f*255999LL + 498LL)/499LL;
        long long i1 = ((long long)(f+1)*255999LL + 498LL)/499LL;
        double wv;
        if(f < 499) wv = (double)(i1 - i0) - (double)Aarr[f] + (f > 0 ? (double)Aarr[f-1] : 0.0);
        else        wv = (double)Aarr[498] + 1.0;
        wfr[f] = (float)(wv / (double)NS);
    }
    __syncthreads();
    const int k = tid & 63, seg = tid >> 6;
    float acc = 0.f;
    for(int f = seg*125; f < seg*125 + 125; ++f)
        acc += wfr[f] * fm[(b*500 + f)*64 + k];
    part[seg*64 + k] = acc;
    __syncthreads();
    if(tid < 64) mm[b*64 + tid] = part[tid] + part[64+tid] + part[128+tid] + part[192+tid];
}

// ---------------------------------------------------------------------------
// L1: blocks 0..3 -> kT1; blocks 4..503 -> kA (fwd 512-FFT + twiddle,
// position-order coalesced store). One s_barrier in the kA path.
// ---------------------------------------------------------------------------
__global__ __launch_bounds__(256) void kAT(const float* __restrict__ fm,
                                           const float* __restrict__ noise,
                                           cplx* __restrict__ Y,
                                           float* __restrict__ mm){
    __shared__ cplx sTab[512];
    __shared__ cplx sU[4][545];
    const int tid = threadIdx.x;
    if(blockIdx.x < 4){
        dev_kT1(fm, mm, blockIdx.x, tid, (float*)&sU[0][0]);
        return;
    }
    const int item = blockIdx.x - 4;
    const int lane = tid & 63, w = tid >> 6;
    const int b = item / 125;
    const int n2base = (item - b*125) * 4;
    build_tab<512>(sTab, tid);
    const float* xb = noise + b*NS + n2base;
    for(int i = tid; i < 512*4; i += 256){
        int n1 = i >> 2, ws = i & 3;
        sU[ws][PX(n1)] = make_float2(xb[n1*500 + ws], 0.f);
    }
    __syncthreads();
    cplx* Uw = sU[w];
    wstage<8,512, 1,false,512>(Uw, sTab, lane); wave_fence();
    wstage<8, 64, 8,false,512>(Uw, sTab, lane); wave_fence();
    wstage<8,  8,64,false,512>(Uw, sTab, lane); wave_fence();
    const int n2 = n2base + w;
    cplx* yp = Y + (b*N2 + n2)*N1;
    const float tw = -2.f*PI_F/(float)NS;
#pragma unroll
    for(int t = 0; t < 8; ++t){
        int p = lane + 64*t;
        int k1 = rev8_3(p);
        cplx v = Uw[PX(p)];
        v = crotf(v, tw*(float)(n2*k1));
        yp[p] = v;
    }
}

// ---------------------------------------------------------------------------
// L2: one block per p1 (512 blocks); 4 waves = 4 batches of the same k1-column.
// Gaussian-filterbank H computed ONCE per (k1,p), shared across batches.
// Two s_barriers total; wave fences between stages.
// ---------------------------------------------------------------------------
__global__ __launch_bounds__(256) void kB2(cplx* __restrict__ Y,
                                           const float* __restrict__ mm){
    __shared__ cplx sTab[512];
    __shared__ cplx sU[4][537];
    __shared__ float sMM[256];
    __shared__ float sH[4][500];
    const int p1 = blockIdx.x;
    const int k1 = rev8_3(p1);
    const int tid = threadIdx.x, lane = tid & 63, w = tid >> 6;

    // phase 1: stage mm, build tab, load own column (wave w = batch w)
    sMM[tid] = mm[tid];
    build_tab<500>(sTab, tid);
    cplx* Uw = sU[w];
#pragma unroll
    for(int t = 0; t < 8; ++t){
        int n2 = lane + 64*t;
        if(n2 < 500) Uw[PX(n2)] = Y[(size_t)(w*N2 + n2)*N1 + p1];
    }
    __syncthreads();      // sMM/tab/columns all visible

    // forward 500-FFT (wave-private)
    wstage<5,500,  1,false,500>(Uw, sTab, lane); wave_fence();
    wstage<5,100,  5,false,500>(Uw, sTab, lane); wave_fence();
    wstage<5, 20, 25,false,500>(Uw, sTab, lane); wave_fence();
    wstage<4,  4,125,false,500>(Uw, sTab, lane); wave_fence();

    // cooperative H: logff[j] = L0 + L1*j (exact ln of the logspace freqs)
    {
        const float L0 = 2.99573227355399099f;     // ln(20)
        const float L1 = 0.100196159912887067f;    // ln(11025/20)/63
        const float invN = 1.f/(float)NS;
        for(int p = tid; p < 500; p += 256){
            int t1 = p/100; int r = p - 100*t1;
            int t2 = r/20;  r -= 20*t2;
            int t3 = r>>2;  int t4 = r & 3;
            int k2 = t1 + 5*t2 + 25*t3 + 125*t4;
            int kf = k1 + N1*k2;
            int kk = min(kf, NS - kf);
            float lf = logf((float)kk*(22050.f/(float)NS) + 1e-7f);
            float wsum = 0.f, w0 = 0.f, w1 = 0.f, w2 = 0.f, w3 = 0.f;
#pragma unroll
            for(int j = 0; j < 64; ++j){
                float d = lf - (L0 + L1*(float)j);
                float e = __expf(-2.f*d*d);
                wsum += e;
                w0 += e*sMM[j]; w1 += e*sMM[64+j]; w2 += e*sMM[128+j]; w3 += e*sMM[192+j];
            }
            float inv = invN/(wsum + 1e-7f);
            sH[0][p] = w0*inv; sH[1][p] = w1*inv; sH[2][p] = w2*inv; sH[3][p] = w3*inv;
        }
    }
    __syncthreads();      // sH ready (also orders the fwd-FFT columns)

    // apply H, inverse FFT, inverse twiddle, store
#pragma unroll
    for(int t = 0; t < 8; ++t){
        int p = lane + 64*t;
        if(p < 500){
            float h = sH[w][p];
            cplx v = Uw[PX(p)];
            Uw[PX(p)] = make_float2(v.x*h, v.y*h);
        }
    }
    wave_fence();
    wstage<4,  4,125,true,500>(Uw, sTab, lane); wave_fence();
    wstage<5, 20, 25,true,500>(Uw, sTab, lane); wave_fence();
    wstage<5,100,  5,true,500>(Uw, sTab, lane); wave_fence();
    wstage<5,500,  1,true,500>(Uw, sTab, lane); wave_fence();
    const float tw = 2.f*PI_F/(float)NS;
#pragma unroll
    for(int t = 0; t < 8; ++t){
        int n2 = lane + 64*t;
        if(n2 < 500){
            cplx v = Uw[PX(n2)];
            v = crotf(v, tw*(float)(n2*k1));
            Y[(size_t)(w*N2 + n2)*N1 + p1] = v;
        }
    }
}

// ---------------------------------------------------------------------------
// L3: inverse 512-FFT per n2-column (DIT consumes position order), real out.
// Two s_barriers; wave fences between stages.
// ---------------------------------------------------------------------------
__global__ __launch_bounds__(256) void kC2(const cplx* __restrict__ Y,
                                           float* __restrict__ out){
    __shared__ cplx sTab[512];
    __shared__ cplx sU[4][545];
    const int tid = threadIdx.x, lane = tid & 63, w = tid >> 6;
    const int item = blockIdx.x;
    const int b = item / 125;
    const int n2base = (item - b*125) * 4;
    build_tab<512>(sTab, tid);
    cplx* Uw = sU[w];
    {
        const cplx* yp = Y + (b*N2 + n2base + w)*N1;
#pragma unroll
        for(int t = 0; t < 8; ++t){
            int p = lane + 64*t;
            Uw[PX(p)] = yp[p];
        }
    }
    __syncthreads();      // tab ready; own column loaded
    wstage<8,  8,64,true,512>(Uw, sTab, lane); wave_fence();
    wstage<8, 64, 8,true,512>(Uw, sTab, lane); wave_fence();
    wstage<8,512, 1,true,512>(Uw, sTab, lane);
    __syncthreads();      // columns complete before cross-wave tiled store
    float* ob = out + b*NS + n2base;
    for(int i = tid; i < 512*4; i += 256){
        int n1 = i >> 2, ws = i & 3;
        ob[n1*500 + ws] = sU[ws][PX(n1)].x;
    }
}

// ---------------------------------------------------------------------------
extern "C" void kernel_launch(void* const* d_in, const int* in_sizes, int n_in,
                              void* d_out, int out_size, void* d_ws, size_t ws_size,
                              hipStream_t stream) {
    const float* fm = (const float*)d_in[0];     // (4,500,64)
    const float* noise = (const float*)d_in[1];  // (4,256000)
    float* out = (float*)d_out;

    char* ws = (char*)d_ws;
    cplx*  Y  = (cplx*)ws;                       //  8,192,000 B
    float* mm = (float*)(ws + 8192000);          //      1,024 B

    kAT<<<504, 256, 0, stream>>>(fm, noise, Y, mm);
    kB2<<<512, 256, 0, stream>>>(Y, mm);
    kC2<<<500, 256, 0, stream>>>(Y, out);
}

// Round 8
// 111.743 us; speedup vs baseline: 1.7099x; 1.0464x over previous
//
#include <hip/hip_runtime.h>
#include <math.h>

#define NS 256000
#define N1 512            // FFT over n1: radix 8,8,8
#define N2 500            // FFT over n2: radices 5,5,5,4
#define PI_F 3.14159265358979323846f

typedef float2 cplx;

__device__ __forceinline__ cplx cadd(cplx a, cplx b){ return make_float2(a.x+b.x, a.y+b.y); }
__device__ __forceinline__ cplx csub(cplx a, cplx b){ return make_float2(a.x-b.x, a.y-b.y); }
__device__ __forceinline__ cplx cmul(cplx a, cplx b){ return make_float2(a.x*b.x-a.y*b.y, a.x*b.y+a.y*b.x); }
__device__ __forceinline__ cplx cmulc(cplx a, cplx b){ return make_float2(a.x*b.x+a.y*b.y, a.y*b.x-a.x*b.y); }
__device__ __forceinline__ cplx crotf(cplx v, float ang){
    float sn = __sinf(ang), cs = __cosf(ang);
    return make_float2(v.x*cs - v.y*sn, v.x*sn + v.y*cs);
}
__device__ __forceinline__ int PX(int e){ return e + (e>>4); }
__device__ __forceinline__ int rev8_3(int k){ return ((k&7)<<6) | (k&0x38) | (k>>6); }

// Intra-wave LDS fence: DS pipe is in-order per wave; drain own DS writes and
// pin compiler ordering. 0xC07F = vmcnt(63) expcnt(7) lgkmcnt(0).
__device__ __forceinline__ void wave_fence(){
    __builtin_amdgcn_s_waitcnt(0xC07F);
    __builtin_amdgcn_wave_barrier();
}

template<bool INV>
__device__ __forceinline__ void dft4(const cplx* a, cplx* b){
    cplx t0=cadd(a[0],a[2]), t1=csub(a[0],a[2]), t2=cadd(a[1],a[3]), t3=csub(a[1],a[3]);
    b[0]=cadd(t0,t2); b[2]=csub(t0,t2);
    if(!INV){ b[1]=make_float2(t1.x+t3.y, t1.y-t3.x); b[3]=make_float2(t1.x-t3.y, t1.y+t3.x); }
    else    { b[1]=make_float2(t1.x-t3.y, t1.y+t3.x); b[3]=make_float2(t1.x+t3.y, t1.y-t3.x); }
}

template<bool INV>
__device__ __forceinline__ void dft8(const cplx* a, cplx* b){
    cplx ev[4]={a[0],a[2],a[4],a[6]}, od[4]={a[1],a[3],a[5],a[7]};
    cplx C[4], D[4];
    dft4<INV>(ev, C); dft4<INV>(od, D);
    const float s = 0.70710678118654752f;
    const float sg = INV ? 1.f : -1.f;
    cplx d1 = cmul(D[1], make_float2( s, sg*s));
    cplx d2 = cmul(D[2], make_float2(0.f, sg ));
    cplx d3 = cmul(D[3], make_float2(-s, sg*s));
    b[0]=cadd(C[0],D[0]); b[4]=csub(C[0],D[0]);
    b[1]=cadd(C[1],d1);   b[5]=csub(C[1],d1);
    b[2]=cadd(C[2],d2);   b[6]=csub(C[2],d2);
    b[3]=cadd(C[3],d3);   b[7]=csub(C[3],d3);
}

template<bool INV>
__device__ __forceinline__ void dft5(const cplx* a, cplx* b){
    const float c1=0.30901699437494742f, s1=0.95105651629515357f;
    const float c2=-0.80901699437494745f, s2=0.58778525229247312f;
    const float sg = INV ? 1.f : -1.f;
    cplx W[5];
    W[0]=make_float2(1.f,0.f);
    W[1]=make_float2(c1, sg*s1); W[2]=make_float2(c2, sg*s2);
    W[3]=make_float2(c2,-sg*s2); W[4]=make_float2(c1,-sg*s1);
#pragma unroll
    for(int u=0;u<5;++u){
        cplx acc = a[0];
        int idx = 0;
#pragma unroll
        for(int r=1;r<5;++r){
            idx += u; if(idx >= 5) idx -= 5;
            acc = cadd(acc, cmul(a[r], W[idx]));
        }
        b[u] = acc;
    }
}

// In-place stage on a wave-private LDS column. wave_fence() between stages.
template<int R, int L, int TMUL, bool INV, int NN>
__device__ __forceinline__ void wstage(cplx* Uw, const cplx* tab, int lane){
    constexpr int m = L / R;
    constexpr int nb = NN / R;
#pragma unroll
    for(int it = 0; it < (nb + 63) / 64; ++it){
        int beta = lane + it*64;
        if(beta < nb){
            int blk = beta / m;
            int j = beta - blk*m;
            int base = blk*L + j;
            cplx a[R];
#pragma unroll
            for(int t=0;t<R;++t) a[t] = Uw[PX(base + m*t)];
            if(INV){
#pragma unroll
                for(int t=1;t<R;++t) a[t] = cmulc(a[t], tab[TMUL*j*t]);
            }
            cplx bb[R];
            if constexpr (R==4) dft4<INV>(a,bb);
            else if constexpr (R==5) dft5<INV>(a,bb);
            else dft8<INV>(a,bb);
            if(!INV){
#pragma unroll
                for(int t=1;t<R;++t) bb[t] = cmul(bb[t], tab[TMUL*j*t]);
            }
#pragma unroll
            for(int t=0;t<R;++t) Uw[PX(base + m*t)] = bb[t];
        }
    }
}

template<int NTAB, int NTHR>
__device__ __forceinline__ void build_tab(cplx* tab, int tid){
    const float step = -2.f*PI_F/(float)NTAB;
    for(int i = tid; i < NTAB; i += NTHR){
        float a = step*(float)i;
        tab[i] = make_float2(__cosf(a), __sinf(a));
    }
}

__device__ void dev_kT1(const float* __restrict__ fm, float* __restrict__ mm,
                        int b, int tid, float* scratch){
    float* Aarr = scratch;          // 500
    float* wfr  = scratch + 500;    // 500
    float* part = scratch + 1000;   // 256
    for(int f = tid; f < 500; f += 256){
        long long i0 = ((long long)f*255999LL + 498LL)/499LL;
        long long i1 = ((long long)(f+1)*255999LL + 498LL)/499LL;
        long long cnt = i1 - i0;
        long long sumi = (i0 + i1 - 1)*cnt/2;
        long long num = 499LL*sumi - cnt*(long long)f*255999LL;
        Aarr[f] = (float)((double)num / 255999.0);
    }
    __syncthreads();
    for(int f = tid; f < 500; f += 256){
        long long i0 = ((long long)f*255999LL + 498LL)/499LL;
        long long i1 = ((long long)(f+1)*255999LL + 498LL)/499LL;
        double wv;
        if(f < 499) wv = (double)(i1 - i0) - (double)Aarr[f] + (f > 0 ? (double)Aarr[f-1] : 0.0);
        else        wv = (double)Aarr[498] + 1.0;
        wfr[f] = (float)(wv / (double)NS);
    }
    __syncthreads();
    const int k = tid & 63, seg = tid >> 6;
    float acc = 0.f;
    for(int f = seg*125; f < seg*125 + 125; ++f)
        acc += wfr[f] * fm[(b*500 + f)*64 + k];
    part[seg*64 + k] = acc;
    __syncthreads();
    if(tid < 64) mm[b*64 + tid] = part[tid] + part[64+tid] + part[128+tid] + part[192+tid];
}

// ---------------------------------------------------------------------------
// L1: blocks 0..3 -> kT1; blocks 4..503 -> kA (fwd 512-FFT + twiddle,
// position-order coalesced store). One s_barrier in the kA path.
// ---------------------------------------------------------------------------
__global__ __launch_bounds__(256) void kAT(const float* __restrict__ fm,
                                           const float* __restrict__ noise,
                                           cplx* __restrict__ Y,
                                           float* __restrict__ mm){
    __shared__ cplx sTab[512];
    __shared__ cplx sU[4][545];
    const int tid = threadIdx.x;
    if(blockIdx.x < 4){
        dev_kT1(fm, mm, blockIdx.x, tid, (float*)&sU[0][0]);
        return;
    }
    const int item = blockIdx.x - 4;
    const int lane = tid & 63, w = tid >> 6;
    const int b = item / 125;
    const int n2base = (item - b*125) * 4;
    build_tab<512,256>(sTab, tid);
    const float* xb = noise + b*NS + n2base;
    for(int i = tid; i < 512*4; i += 256){
        int n1 = i >> 2, ws = i & 3;
        sU[ws][PX(n1)] = make_float2(xb[n1*500 + ws], 0.f);
    }
    __syncthreads();
    cplx* Uw = sU[w];
    wstage<8,512, 1,false,512>(Uw, sTab, lane); wave_fence();
    wstage<8, 64, 8,false,512>(Uw, sTab, lane); wave_fence();
    wstage<8,  8,64,false,512>(Uw, sTab, lane); wave_fence();
    const int n2 = n2base + w;
    cplx* yp = Y + (b*N2 + n2)*N1;
    const float tw = -2.f*PI_F/(float)NS;
#pragma unroll
    for(int t = 0; t < 8; ++t){
        int p = lane + 64*t;
        int k1 = rev8_3(p);
        cplx v = Uw[PX(p)];
        v = crotf(v, tw*(float)(n2*k1));
        yp[p] = v;
    }
}

// ---------------------------------------------------------------------------
// L2 (kB3): grid (64,4) x 512 thr. Block = 8 consecutive p1-columns of one
// batch; 8 consecutive threads = one aligned 64 B line of Y on load/store.
// Wave w owns column p1base+w: fwd 500-FFT, inline Gaussian H (broadcast sMM),
// inv 500-FFT, wave-private inverse twiddle. Two s_barriers.
// ---------------------------------------------------------------------------
__global__ __launch_bounds__(512) void kB3(cplx* __restrict__ Y,
                                           const float* __restrict__ mm){
    __shared__ cplx sTab[512];
    __shared__ cplx sU[8][537];
    __shared__ float sMM[64];
    const int p1base = blockIdx.x * 8;
    const int b = blockIdx.y;
    const int tid = threadIdx.x, lane = tid & 63, w = tid >> 6;

    if(tid < 64) sMM[tid] = mm[b*64 + tid];
    build_tab<500,512>(sTab, tid);
    // coop line-granular load: 8 threads = 64 B line
    cplx* yb = Y + (size_t)b*NS;
    for(int i = tid; i < 4000; i += 512){
        int n2 = i >> 3, off = i & 7;
        sU[off][PX(n2)] = yb[(size_t)n2*N1 + p1base + off];
    }
    __syncthreads();

    cplx* Uw = sU[w];
    const int k1 = rev8_3(p1base + w);
    // forward 500-FFT (wave-private)
    wstage<5,500,  1,false,500>(Uw, sTab, lane); wave_fence();
    wstage<5,100,  5,false,500>(Uw, sTab, lane); wave_fence();
    wstage<5, 20, 25,false,500>(Uw, sTab, lane); wave_fence();
    wstage<4,  4,125,false,500>(Uw, sTab, lane); wave_fence();

    // inline H: position p -> k2; logff[j] = L0 + L1*j; sMM broadcast reads
    {
        const float L0 = 2.99573227355399099f;     // ln(20)
        const float L1 = 0.100196159912887067f;    // ln(11025/20)/63
        const float invN = 1.f/(float)NS;
#pragma unroll
        for(int t = 0; t < 8; ++t){
            int p = lane + 64*t;
            if(p < 500){
                int t1 = p/100; int r = p - 100*t1;
                int t2 = r/20;  r -= 20*t2;
                int t3 = r>>2;  int t4 = r & 3;
                int k2 = t1 + 5*t2 + 25*t3 + 125*t4;
                int kf = k1 + N1*k2;
                int kk = min(kf, NS - kf);
                float lf = logf((float)kk*(22050.f/(float)NS) + 1e-7f);
                float wsum = 0.f, wm = 0.f;
#pragma unroll
                for(int j = 0; j < 64; ++j){
                    float d = lf - (L0 + L1*(float)j);
                    float e = __expf(-2.f*d*d);
                    wsum += e;
                    wm += e*sMM[j];
                }
                float h = wm/(wsum + 1e-7f)*invN;
                cplx v = Uw[PX(p)];
                Uw[PX(p)] = make_float2(v.x*h, v.y*h);
            }
        }
    }
    wave_fence();
    // inverse 500-FFT
    wstage<4,  4,125,true,500>(Uw, sTab, lane); wave_fence();
    wstage<5, 20, 25,true,500>(Uw, sTab, lane); wave_fence();
    wstage<5,100,  5,true,500>(Uw, sTab, lane); wave_fence();
    wstage<5,500,  1,true,500>(Uw, sTab, lane); wave_fence();
    // wave-private inverse inter-pass twiddle
    {
        const float tw = 2.f*PI_F/(float)NS;
#pragma unroll
        for(int t = 0; t < 8; ++t){
            int n2 = lane + 64*t;
            if(n2 < 500) Uw[PX(n2)] = crotf(Uw[PX(n2)], tw*(float)(n2*k1));
        }
    }
    __syncthreads();
    // coop line-granular store
    for(int i = tid; i < 4000; i += 512){
        int n2 = i >> 3, off = i & 7;
        yb[(size_t)n2*N1 + p1base + off] = sU[off][PX(n2)];
    }
}

// ---------------------------------------------------------------------------
// L3: inverse 512-FFT per n2-column (DIT consumes position order), real out.
// ---------------------------------------------------------------------------
__global__ __launch_bounds__(256) void kC2(const cplx* __restrict__ Y,
                                           float* __restrict__ out){
    __shared__ cplx sTab[512];
    __shared__ cplx sU[4][545];
    const int tid = threadIdx.x, lane = tid & 63, w = tid >> 6;
    const int item = blockIdx.x;
    const int b = item / 125;
    const int n2base = (item - b*125) * 4;
    build_tab<512,256>(sTab, tid);
    cplx* Uw = sU[w];
    {
        const cplx* yp = Y + (b*N2 + n2base + w)*N1;
#pragma unroll
        for(int t = 0; t < 8; ++t){
            int p = lane + 64*t;
            Uw[PX(p)] = yp[p];
        }
    }
    __syncthreads();      // tab ready; own column loaded
    wstage<8,  8,64,true,512>(Uw, sTab, lane); wave_fence();
    wstage<8, 64, 8,true,512>(Uw, sTab, lane); wave_fence();
    wstage<8,512, 1,true,512>(Uw, sTab, lane);
    __syncthreads();      // columns complete before cross-wave tiled store
    float* ob = out + b*NS + n2base;
    for(int i = tid; i < 512*4; i += 256){
        int n1 = i >> 2, ws = i & 3;
        ob[n1*500 + ws] = sU[ws][PX(n1)].x;
    }
}

// ---------------------------------------------------------------------------
extern "C" void kernel_launch(void* const* d_in, const int* in_sizes, int n_in,
                              void* d_out, int out_size, void* d_ws, size_t ws_size,
                              hipStream_t stream) {
    const float* fm = (const float*)d_in[0];     // (4,500,64)
    const float* noise = (const float*)d_in[1];  // (4,256000)
    float* out = (float*)d_out;

    char* ws = (char*)d_ws;
    cplx*  Y  = (cplx*)ws;                       //  8,192,000 B
    float* mm = (float*)(ws + 8192000);          //      1,024 B

    kAT<<<504, 256, 0, stream>>>(fm, noise, Y, mm);
    kB3<<<dim3(64,4), 512, 0, stream>>>(Y, mm);
    kC2<<<500, 256, 0, stream>>>(Y, out);
}